// Round 4
// baseline (2347.157 us; speedup 1.0000x reference)
//
#include <hip/hip_runtime.h>

typedef unsigned short u16;
typedef unsigned int   u32;
typedef __bf16 bf16x8 __attribute__((ext_vector_type(8)));
typedef float  f32x4  __attribute__((ext_vector_type(4)));
typedef u32    u32x2  __attribute__((ext_vector_type(2)));

#define DIMD  256
#define DIMH  512
#define MTILE 64
#define NTHREADS 512

// LDS (u16 units). Row strides padded +16B.
#define USTR 264
#define HSTR 520
#define U_BASE 0
#define H_BASE (MTILE*USTR)             // 16896
#define LDS_U16 (H_BASE + MTILE*HSTR)   // 50176 u16 = 100352 B -> 1 WG/CU

#define DT 0.0625f

__device__ __forceinline__ u16 f2bf(float f) {          // RTN fp32->bf16
  u32 u = __float_as_uint(f);
  u += 0x7FFFu + ((u >> 16) & 1u);
  return (u16)(u >> 16);
}
__device__ __forceinline__ u32 pk(float a, float b) {
  return (u32)f2bf(a) | ((u32)f2bf(b) << 16);
}
__device__ __forceinline__ float bflo(u32 p) { return __uint_as_float(p << 16); }
__device__ __forceinline__ float bfhi(u32 p) { return __uint_as_float(p & 0xFFFF0000u); }
__device__ __forceinline__ float tanh_fast(float x) {
  float e = __builtin_amdgcn_exp2f(x * 2.8853900817779268f);  // 2*log2(e)
  return 1.0f - 2.0f * __builtin_amdgcn_rcpf(e + 1.0f);
}

// W1[256][512] -> W1T bf16 [hcol=512][k=256]; W2[512][256] -> W2T bf16 [dcol=256][k=512]
__global__ void convert_w(const float* __restrict__ W1, const float* __restrict__ W2,
                          u16* __restrict__ w1t, u16* __restrict__ w2t) {
  int idx = blockIdx.x * 256 + threadIdx.x;
  {
    int n = idx >> 8, k = idx & 255;
    w1t[idx] = f2bf(W1[k * DIMH + n]);
  }
  {
    int n = idx >> 9, k = idx & 511;
    w2t[idx] = f2bf(W2[k * DIMD + n]);
  }
}

// 1 WG/CU (LDS-limited) => 8 waves/CU = 2 waves/SIMD. Pin the allocator to
// that occupancy so it uses the full 256-reg unified budget instead of
// spilling to scratch (rounds 1-3: 6-9 GB of HBM spill traffic at VGPR=128).
__global__ __attribute__((amdgpu_flat_work_group_size(NTHREADS, NTHREADS),
                          amdgpu_waves_per_eu(2, 2)))
void ode_fused(
    const float* __restrict__ x,   const float* __restrict__ b1,
    const float* __restrict__ b2,  const float* __restrict__ wfc,
    const float* __restrict__ bfc, const u16* __restrict__ w1t,
    const u16* __restrict__ w2t,   float* __restrict__ out)
{
  __shared__ u16 lds[LDS_U16];

  const int tid   = threadIdx.x;
  const int wg    = blockIdx.x;
  const int wv    = tid >> 6;          // wave 0..7
  const int lane  = tid & 63;
  const int lanel = lane & 15;
  const int laneq = lane >> 4;

  // Thread's owned positions (= its GEMM2 C/D fragment):
  //   rows:  nb*16 + lanel               (nb 0..3)
  //   dcols: wv*32 + mb*16 + laneq*4 + r (mb 0..1, r 0..3)
  // flat index i = nb*8 + mb*4 + r ; packed pair p = i>>1 = nb*4 + mb*2 + (r>>1)

  u32 b1p[8], b2p[4];
#pragma unroll
  for (int mb = 0; mb < 4; ++mb) {
    int base = wv * 64 + mb * 16 + laneq * 4;
    b1p[mb * 2 + 0] = pk(b1[base + 0], b1[base + 1]);
    b1p[mb * 2 + 1] = pk(b1[base + 2], b1[base + 3]);
  }
#pragma unroll
  for (int mb = 0; mb < 2; ++mb) {
    int base = wv * 32 + mb * 16 + laneq * 4;
    b2p[mb * 2 + 0] = pk(b2[base + 0], b2[base + 1]);
    b2p[mb * 2 + 1] = pk(b2[base + 2], b2[base + 3]);
  }

  // y in fp32 registers (precision anchor)
  float yv[32];
#pragma unroll
  for (int nb = 0; nb < 4; ++nb)
#pragma unroll
    for (int mb = 0; mb < 2; ++mb) {
      const float4 v = *(const float4*)&x[(wg * 64 + nb * 16 + lanel) * DIMD +
                                          wv * 32 + mb * 16 + laneq * 4];
      int i = nb * 8 + mb * 4;
      yv[i + 0] = v.x; yv[i + 1] = v.y; yv[i + 2] = v.z; yv[i + 3] = v.w;
    }

  // write u1 = bf16(y)
#pragma unroll
  for (int nb = 0; nb < 4; ++nb)
#pragma unroll
    for (int mb = 0; mb < 2; ++mb) {
      int i = nb * 8 + mb * 4;
      u32x2 w; w.x = pk(yv[i], yv[i + 1]); w.y = pk(yv[i + 2], yv[i + 3]);
      *(u32x2*)&lds[U_BASE + (nb * 16 + lanel) * USTR + wv * 32 + mb * 16 + laneq * 4] = w;
    }
  __syncthreads();

  const u16* w1base[4];
#pragma unroll
  for (int mb = 0; mb < 4; ++mb)
    w1base[mb] = w1t + (wv * 64 + mb * 16 + lanel) * DIMD + laneq * 8;
  const u16* w2base[2];
#pragma unroll
  for (int mb = 0; mb < 2; ++mb)
    w2base[mb] = w2t + (wv * 32 + mb * 16 + lanel) * DIMH + laneq * 8;

  // Loop-carried k-state, manually unioned to 48 u32:
  //   st[0:16)  = k1 packed (s1..s4), then u6d packed (s4..s5)
  //   st[16:32) = k2 packed (s2..s4)
  //   st[32:48) = k3 packed (s3..s4)
  u32 st[48];

#pragma unroll 1
  for (int step = 0; step < 16; ++step) {
#pragma unroll 1
    for (int s = 1; s <= 6; ++s) {
      // ---------- GEMM1': D[hcol][row] = W1T(A,global) x u(B,LDS) ----------
      f32x4 acc[4][4];
#pragma unroll
      for (int mb = 0; mb < 4; ++mb)
#pragma unroll
        for (int nb = 0; nb < 4; ++nb) acc[mb][nb] = (f32x4){0.f, 0.f, 0.f, 0.f};
#pragma unroll
      for (int kk = 0; kk < 8; ++kk) {
        bf16x8 a[4], bu[4];
#pragma unroll
        for (int mb = 0; mb < 4; ++mb)
          a[mb] = *(const bf16x8*)(w1base[mb] + kk * 32);
#pragma unroll
        for (int nb = 0; nb < 4; ++nb)
          bu[nb] = *(const bf16x8*)&lds[U_BASE + (nb * 16 + lanel) * USTR + kk * 32 + laneq * 8];
#pragma unroll
        for (int mb = 0; mb < 4; ++mb)
#pragma unroll
          for (int nb = 0; nb < 4; ++nb)
            acc[mb][nb] = __builtin_amdgcn_mfma_f32_16x16x32_bf16(a[mb], bu[nb], acc[mb][nb], 0, 0, 0);
      }
      // epilogue1: h = tanh(acc + b1)
#pragma unroll
      for (int mb = 0; mb < 4; ++mb)
#pragma unroll
        for (int nb = 0; nb < 4; ++nb) {
          float h0 = tanh_fast(acc[mb][nb][0] + bflo(b1p[mb * 2 + 0]));
          float h1 = tanh_fast(acc[mb][nb][1] + bfhi(b1p[mb * 2 + 0]));
          float h2 = tanh_fast(acc[mb][nb][2] + bflo(b1p[mb * 2 + 1]));
          float h3 = tanh_fast(acc[mb][nb][3] + bfhi(b1p[mb * 2 + 1]));
          u32x2 w; w.x = pk(h0, h1); w.y = pk(h2, h3);
          *(u32x2*)&lds[H_BASE + (nb * 16 + lanel) * HSTR + wv * 64 + mb * 16 + laneq * 4] = w;
        }
      __syncthreads();   // h visible; all GEMM1 u-reads done

      // ---------- GEMM2': D[dcol][row] = W2T(A,global) x h(B,LDS) ----------
      f32x4 acc2[2][4];
#pragma unroll
      for (int mb = 0; mb < 2; ++mb)
#pragma unroll
        for (int nb = 0; nb < 4; ++nb) acc2[mb][nb] = (f32x4){0.f, 0.f, 0.f, 0.f};
#pragma unroll
      for (int kk = 0; kk < 16; ++kk) {
        bf16x8 a2[2], bh[4];
#pragma unroll
        for (int mb = 0; mb < 2; ++mb)
          a2[mb] = *(const bf16x8*)(w2base[mb] + kk * 32);
#pragma unroll
        for (int nb = 0; nb < 4; ++nb)
          bh[nb] = *(const bf16x8*)&lds[H_BASE + (nb * 16 + lanel) * HSTR + kk * 32 + laneq * 8];
#pragma unroll
        for (int mb = 0; mb < 2; ++mb)
#pragma unroll
          for (int nb = 0; nb < 4; ++nb)
            acc2[mb][nb] = __builtin_amdgcn_mfma_f32_16x16x32_bf16(a2[mb], bh[nb], acc2[mb][nb], 0, 0, 0);
      }

      // ---------- fused epilogue2 + stage epilogue (no kc/uo temp arrays) ----
      // Per fragment: k = acc2 + b2 ; build u (or y update) ; pack ; write LDS.
      if (s == 1) {
        const float C = DT * 0.2f;
#pragma unroll
        for (int mb = 0; mb < 2; ++mb)
#pragma unroll
          for (int nb = 0; nb < 4; ++nb) {
            int i = nb * 8 + mb * 4, p = nb * 4 + mb * 2;
            float k0 = acc2[mb][nb][0] + bflo(b2p[mb * 2 + 0]);
            float k1 = acc2[mb][nb][1] + bfhi(b2p[mb * 2 + 0]);
            float k2 = acc2[mb][nb][2] + bflo(b2p[mb * 2 + 1]);
            float k3 = acc2[mb][nb][3] + bfhi(b2p[mb * 2 + 1]);
            st[p] = pk(k0, k1); st[p + 1] = pk(k2, k3);
            u32x2 w;
            w.x = pk(yv[i] + C * k0, yv[i + 1] + C * k1);
            w.y = pk(yv[i + 2] + C * k2, yv[i + 3] + C * k3);
            *(u32x2*)&lds[U_BASE + (nb * 16 + lanel) * USTR + wv * 32 + mb * 16 + laneq * 4] = w;
          }
      } else if (s == 2) {
        const float C1 = DT * 0.075f, C2 = DT * 0.225f;
#pragma unroll
        for (int mb = 0; mb < 2; ++mb)
#pragma unroll
          for (int nb = 0; nb < 4; ++nb) {
            int i = nb * 8 + mb * 4, p = nb * 4 + mb * 2;
            float k0 = acc2[mb][nb][0] + bflo(b2p[mb * 2 + 0]);
            float k1 = acc2[mb][nb][1] + bfhi(b2p[mb * 2 + 0]);
            float k2 = acc2[mb][nb][2] + bflo(b2p[mb * 2 + 1]);
            float k3 = acc2[mb][nb][3] + bfhi(b2p[mb * 2 + 1]);
            st[16 + p] = pk(k0, k1); st[16 + p + 1] = pk(k2, k3);
            u32x2 w;
            w.x = pk(yv[i]     + C1 * bflo(st[p])     + C2 * k0,
                     yv[i + 1] + C1 * bfhi(st[p])     + C2 * k1);
            w.y = pk(yv[i + 2] + C1 * bflo(st[p + 1]) + C2 * k2,
                     yv[i + 3] + C1 * bfhi(st[p + 1]) + C2 * k3);
            *(u32x2*)&lds[U_BASE + (nb * 16 + lanel) * USTR + wv * 32 + mb * 16 + laneq * 4] = w;
          }
      } else if (s == 3) {
        const float C1 = DT * (float)(44.0/45.0);
        const float C2 = DT * (float)(-56.0/15.0);
        const float C3 = DT * (float)(32.0/9.0);
#pragma unroll
        for (int mb = 0; mb < 2; ++mb)
#pragma unroll
          for (int nb = 0; nb < 4; ++nb) {
            int i = nb * 8 + mb * 4, p = nb * 4 + mb * 2;
            float k0 = acc2[mb][nb][0] + bflo(b2p[mb * 2 + 0]);
            float k1 = acc2[mb][nb][1] + bfhi(b2p[mb * 2 + 0]);
            float k2 = acc2[mb][nb][2] + bflo(b2p[mb * 2 + 1]);
            float k3 = acc2[mb][nb][3] + bfhi(b2p[mb * 2 + 1]);
            st[32 + p] = pk(k0, k1); st[32 + p + 1] = pk(k2, k3);
            u32x2 w;
            w.x = pk(yv[i]     + C1 * bflo(st[p])     + C2 * bflo(st[16 + p])     + C3 * k0,
                     yv[i + 1] + C1 * bfhi(st[p])     + C2 * bfhi(st[16 + p])     + C3 * k1);
            w.y = pk(yv[i + 2] + C1 * bflo(st[p + 1]) + C2 * bflo(st[16 + p + 1]) + C3 * k2,
                     yv[i + 3] + C1 * bfhi(st[p + 1]) + C2 * bfhi(st[16 + p + 1]) + C3 * k3);
            *(u32x2*)&lds[U_BASE + (nb * 16 + lanel) * USTR + wv * 32 + mb * 16 + laneq * 4] = w;
          }
      } else if (s == 4) {
        // u5; fold k1..k4 into u6-delta and y; k1..k3 die here
        const float C51 = DT * (float)(19372.0/6561.0);
        const float C52 = DT * (float)(-25360.0/2187.0);
        const float C53 = DT * (float)(64448.0/6561.0);
        const float C54 = DT * (float)(-212.0/729.0);
        const float D61 = DT * (float)(9017.0/3168.0  - 35.0/384.0);   // A61-B1
        const float D62 = DT * (float)(-355.0/33.0);                   // A62 (B2=0)
        const float D63 = DT * (float)(46732.0/5247.0 - 500.0/1113.0); // A63-B3
        const float D64 = DT * (float)(49.0/176.0     - 125.0/192.0);  // A64-B4
        const float E1  = DT * (float)(35.0/384.0);
        const float E3  = DT * (float)(500.0/1113.0);
        const float E4  = DT * (float)(125.0/192.0);
#pragma unroll
        for (int mb = 0; mb < 2; ++mb)
#pragma unroll
          for (int nb = 0; nb < 4; ++nb) {
            int i = nb * 8 + mb * 4, p = nb * 4 + mb * 2;
            float k40 = acc2[mb][nb][0] + bflo(b2p[mb * 2 + 0]);
            float k41 = acc2[mb][nb][1] + bfhi(b2p[mb * 2 + 0]);
            float k42 = acc2[mb][nb][2] + bflo(b2p[mb * 2 + 1]);
            float k43 = acc2[mb][nb][3] + bfhi(b2p[mb * 2 + 1]);
            float k10 = bflo(st[p]),      k11 = bfhi(st[p]);
            float k12 = bflo(st[p + 1]),  k13 = bfhi(st[p + 1]);
            float k20 = bflo(st[16 + p]), k21 = bfhi(st[16 + p]);
            float k22 = bflo(st[16 + p + 1]), k23 = bfhi(st[16 + p + 1]);
            float k30 = bflo(st[32 + p]), k31 = bfhi(st[32 + p]);
            float k32 = bflo(st[32 + p + 1]), k33 = bfhi(st[32 + p + 1]);
            u32x2 w;
            w.x = pk(yv[i]     + C51 * k10 + C52 * k20 + C53 * k30 + C54 * k40,
                     yv[i + 1] + C51 * k11 + C52 * k21 + C53 * k31 + C54 * k41);
            w.y = pk(yv[i + 2] + C51 * k12 + C52 * k22 + C53 * k32 + C54 * k42,
                     yv[i + 3] + C51 * k13 + C52 * k23 + C53 * k33 + C54 * k43);
            *(u32x2*)&lds[U_BASE + (nb * 16 + lanel) * USTR + wv * 32 + mb * 16 + laneq * 4] = w;
            st[p]     = pk(D61 * k10 + D62 * k20 + D63 * k30 + D64 * k40,
                           D61 * k11 + D62 * k21 + D63 * k31 + D64 * k41);
            st[p + 1] = pk(D61 * k12 + D62 * k22 + D63 * k32 + D64 * k42,
                           D61 * k13 + D62 * k23 + D63 * k33 + D64 * k43);
            yv[i]     += E1 * k10 + E3 * k30 + E4 * k40;
            yv[i + 1] += E1 * k11 + E3 * k31 + E4 * k41;
            yv[i + 2] += E1 * k12 + E3 * k32 + E4 * k42;
            yv[i + 3] += E1 * k13 + E3 * k33 + E4 * k43;
          }
      } else if (s == 5) {
        const float D65 = DT * (float)(-5103.0/18656.0 + 2187.0/6784.0); // A65-B5
        const float E5  = DT * (float)(-2187.0/6784.0);
#pragma unroll
        for (int mb = 0; mb < 2; ++mb)
#pragma unroll
          for (int nb = 0; nb < 4; ++nb) {
            int i = nb * 8 + mb * 4, p = nb * 4 + mb * 2;
            float k0 = acc2[mb][nb][0] + bflo(b2p[mb * 2 + 0]);
            float k1 = acc2[mb][nb][1] + bfhi(b2p[mb * 2 + 0]);
            float k2 = acc2[mb][nb][2] + bflo(b2p[mb * 2 + 1]);
            float k3 = acc2[mb][nb][3] + bfhi(b2p[mb * 2 + 1]);
            u32x2 w;
            w.x = pk(yv[i]     + bflo(st[p])     + D65 * k0,
                     yv[i + 1] + bfhi(st[p])     + D65 * k1);
            w.y = pk(yv[i + 2] + bflo(st[p + 1]) + D65 * k2,
                     yv[i + 3] + bfhi(st[p + 1]) + D65 * k3);
            *(u32x2*)&lds[U_BASE + (nb * 16 + lanel) * USTR + wv * 32 + mb * 16 + laneq * 4] = w;
            yv[i]     += E5 * k0;
            yv[i + 1] += E5 * k1;
            yv[i + 2] += E5 * k2;
            yv[i + 3] += E5 * k3;
          }
      } else {
        const float E6 = DT * (float)(11.0/84.0);
#pragma unroll
        for (int mb = 0; mb < 2; ++mb)
#pragma unroll
          for (int nb = 0; nb < 4; ++nb) {
            int i = nb * 8 + mb * 4;
            yv[i]     += E6 * (acc2[mb][nb][0] + bflo(b2p[mb * 2 + 0]));
            yv[i + 1] += E6 * (acc2[mb][nb][1] + bfhi(b2p[mb * 2 + 0]));
            yv[i + 2] += E6 * (acc2[mb][nb][2] + bflo(b2p[mb * 2 + 1]));
            yv[i + 3] += E6 * (acc2[mb][nb][3] + bfhi(b2p[mb * 2 + 1]));
            u32x2 w;
            w.x = pk(yv[i], yv[i + 1]); w.y = pk(yv[i + 2], yv[i + 3]);
            *(u32x2*)&lds[U_BASE + (nb * 16 + lanel) * USTR + wv * 32 + mb * 16 + laneq * 4] = w;
          }
      }
      __syncthreads();   // u visible; all GEMM2 h-reads done
    } // stages
  } // steps

  // ---- out[row] = y . Wfc + bfc ----
  {
    float wfcv[8];
#pragma unroll
    for (int mb = 0; mb < 2; ++mb)
#pragma unroll
      for (int r = 0; r < 4; ++r)
        wfcv[mb * 4 + r] = wfc[wv * 32 + mb * 16 + laneq * 4 + r];
    float* redf = (float*)lds;   // safe: last sync drained all U/H readers
    float pr[4];
#pragma unroll
    for (int nb = 0; nb < 4; ++nb) {
      float p = 0.f;
#pragma unroll
      for (int mb = 0; mb < 2; ++mb)
#pragma unroll
        for (int r = 0; r < 4; ++r)
          p += yv[nb * 8 + mb * 4 + r] * wfcv[mb * 4 + r];
      p += __shfl_xor(p, 16);
      p += __shfl_xor(p, 32);
      pr[nb] = p;
    }
    if (laneq == 0) {
#pragma unroll
      for (int nb = 0; nb < 4; ++nb)
        redf[(nb * 16 + lanel) * 8 + wv] = pr[nb];
    }
    __syncthreads();
    if (tid < 64) {
      float s = bfc[0];
#pragma unroll
      for (int w = 0; w < 8; ++w) s += redf[tid * 8 + w];
      out[wg * 64 + tid] = s;
    }
  }
}

extern "C" void kernel_launch(void* const* d_in, const int* in_sizes, int n_in,
                              void* d_out, int out_size, void* d_ws, size_t ws_size,
                              hipStream_t stream) {
  const float* x   = (const float*)d_in[0];
  const float* W1  = (const float*)d_in[1];
  const float* b1  = (const float*)d_in[2];
  const float* W2  = (const float*)d_in[3];
  const float* b2  = (const float*)d_in[4];
  const float* wfc = (const float*)d_in[5];
  const float* bfc = (const float*)d_in[6];
  float* out = (float*)d_out;

  u16* w1t = (u16*)d_ws;                 // [512][256] bf16
  u16* w2t = w1t + DIMH * DIMD;          // [256][512] bf16

  hipLaunchKernelGGL(convert_w, dim3(512), dim3(256), 0, stream, W1, W2, w1t, w2t);
  hipLaunchKernelGGL(ode_fused, dim3(16384 / MTILE), dim3(NTHREADS), 0, stream,
                     x, b1, b2, wfc, bfc, w1t, w2t, out);
}

// Round 5
// 1813.666 us; speedup vs baseline: 1.2942x; 1.2942x over previous
//
#include <hip/hip_runtime.h>

typedef unsigned short u16;
typedef unsigned int   u32;
typedef __bf16 bf16x8 __attribute__((ext_vector_type(8)));
typedef float  f32x4  __attribute__((ext_vector_type(4)));
typedef u32    u32x2  __attribute__((ext_vector_type(2)));

#define DIMD  256
#define DIMH  512
#define MTILE 64
#define NTHREADS 512

// LDS (u16 units). Row strides padded +16B.
#define USTR 264
#define HSTR 520
#define U_BASE 0
#define H_BASE (MTILE*USTR)             // 16896
#define LDS_U16 (H_BASE + MTILE*HSTR)   // 50176 u16 = 100352 B -> 1 WG/CU

#define DT 0.0625f

__device__ __forceinline__ u16 f2bf(float f) {          // RTN fp32->bf16
  u32 u = __float_as_uint(f);
  u += 0x7FFFu + ((u >> 16) & 1u);
  return (u16)(u >> 16);
}
__device__ __forceinline__ u32 pk(float a, float b) {
  return (u32)f2bf(a) | ((u32)f2bf(b) << 16);
}
__device__ __forceinline__ float bflo(u32 p) { return __uint_as_float(p << 16); }
__device__ __forceinline__ float bfhi(u32 p) { return __uint_as_float(p & 0xFFFF0000u); }
__device__ __forceinline__ float tanh_fast(float x) {
  float e = __builtin_amdgcn_exp2f(x * 2.8853900817779268f);  // 2*log2(e)
  return 1.0f - 2.0f * __builtin_amdgcn_rcpf(e + 1.0f);
}

// W1[256][512] -> W1T bf16 [hcol=512][k=256]; W2[512][256] -> W2T bf16 [dcol=256][k=512]
__global__ void convert_w(const float* __restrict__ W1, const float* __restrict__ W2,
                          u16* __restrict__ w1t, u16* __restrict__ w2t) {
  int idx = blockIdx.x * 256 + threadIdx.x;
  {
    int n = idx >> 8, k = idx & 255;
    w1t[idx] = f2bf(W1[k * DIMH + n]);
  }
  {
    int n = idx >> 9, k = idx & 511;
    w2t[idx] = f2bf(W2[k * DIMD + n]);
  }
}

// 1 WG/CU (LDS-limited) => 8 waves/CU = 2 waves/SIMD => 256-reg unified budget.
// kk-loops are `#pragma unroll 1`: full unroll let the scheduler hoist up to
// 8x8 b128 fragment loads (256 regs of in-flight data) on top of ~114
// persistent regs -> guaranteed scratch spills (rounds 1-4: 7-9 GB HBM spill
// traffic). Bounding the window keeps peak pressure ~budget.
__global__ __attribute__((amdgpu_flat_work_group_size(NTHREADS, NTHREADS),
                          amdgpu_waves_per_eu(2, 2)))
void ode_fused(
    const float* __restrict__ x,   const float* __restrict__ b1,
    const float* __restrict__ b2,  const float* __restrict__ wfc,
    const float* __restrict__ bfc, const u16* __restrict__ w1t,
    const u16* __restrict__ w2t,   float* __restrict__ out)
{
  __shared__ u16 lds[LDS_U16];

  const int tid   = threadIdx.x;
  const int wg    = blockIdx.x;
  const int wv    = tid >> 6;          // wave 0..7
  const int lane  = tid & 63;
  const int lanel = lane & 15;
  const int laneq = lane >> 4;

  // Thread's owned positions (= its GEMM2 C/D fragment):
  //   rows:  nb*16 + lanel               (nb 0..3)
  //   dcols: wv*32 + mb*16 + laneq*4 + r (mb 0..1, r 0..3)
  // flat index i = nb*8 + mb*4 + r ; packed pair p = i>>1 = nb*4 + mb*2 + (r>>1)

  u32 b1p[8], b2p[4];
#pragma unroll
  for (int mb = 0; mb < 4; ++mb) {
    int base = wv * 64 + mb * 16 + laneq * 4;
    b1p[mb * 2 + 0] = pk(b1[base + 0], b1[base + 1]);
    b1p[mb * 2 + 1] = pk(b1[base + 2], b1[base + 3]);
  }
#pragma unroll
  for (int mb = 0; mb < 2; ++mb) {
    int base = wv * 32 + mb * 16 + laneq * 4;
    b2p[mb * 2 + 0] = pk(b2[base + 0], b2[base + 1]);
    b2p[mb * 2 + 1] = pk(b2[base + 2], b2[base + 3]);
  }

  // y in fp32 registers (precision anchor)
  float yv[32];
#pragma unroll
  for (int nb = 0; nb < 4; ++nb)
#pragma unroll
    for (int mb = 0; mb < 2; ++mb) {
      const float4 v = *(const float4*)&x[(wg * 64 + nb * 16 + lanel) * DIMD +
                                          wv * 32 + mb * 16 + laneq * 4];
      int i = nb * 8 + mb * 4;
      yv[i + 0] = v.x; yv[i + 1] = v.y; yv[i + 2] = v.z; yv[i + 3] = v.w;
    }

  // write u1 = bf16(y)
#pragma unroll
  for (int nb = 0; nb < 4; ++nb)
#pragma unroll
    for (int mb = 0; mb < 2; ++mb) {
      int i = nb * 8 + mb * 4;
      u32x2 w; w.x = pk(yv[i], yv[i + 1]); w.y = pk(yv[i + 2], yv[i + 3]);
      *(u32x2*)&lds[U_BASE + (nb * 16 + lanel) * USTR + wv * 32 + mb * 16 + laneq * 4] = w;
    }
  __syncthreads();

  const u16* w1base[4];
#pragma unroll
  for (int mb = 0; mb < 4; ++mb)
    w1base[mb] = w1t + (wv * 64 + mb * 16 + lanel) * DIMD + laneq * 8;
  const u16* w2base[2];
#pragma unroll
  for (int mb = 0; mb < 2; ++mb)
    w2base[mb] = w2t + (wv * 32 + mb * 16 + lanel) * DIMH + laneq * 8;

  // Loop-carried k-state, manually unioned to 48 u32:
  //   st[0:16)  = k1 packed (s1..s4), then u6d packed (s4..s5)
  //   st[16:32) = k2 packed (s2..s4)
  //   st[32:48) = k3 packed (s3..s4)
  u32 st[48];

#pragma unroll 1
  for (int step = 0; step < 16; ++step) {
#pragma unroll 1
    for (int s = 1; s <= 6; ++s) {
      // ---------- GEMM1': D[hcol][row] = W1T(A,global) x u(B,LDS) ----------
      f32x4 acc[4][4];
#pragma unroll
      for (int mb = 0; mb < 4; ++mb)
#pragma unroll
        for (int nb = 0; nb < 4; ++nb) acc[mb][nb] = (f32x4){0.f, 0.f, 0.f, 0.f};
#pragma unroll 1
      for (int kk = 0; kk < 8; ++kk) {
        bf16x8 a[4], bu[4];
#pragma unroll
        for (int mb = 0; mb < 4; ++mb)
          a[mb] = *(const bf16x8*)(w1base[mb] + kk * 32);
#pragma unroll
        for (int nb = 0; nb < 4; ++nb)
          bu[nb] = *(const bf16x8*)&lds[U_BASE + (nb * 16 + lanel) * USTR + kk * 32 + laneq * 8];
#pragma unroll
        for (int mb = 0; mb < 4; ++mb)
#pragma unroll
          for (int nb = 0; nb < 4; ++nb)
            acc[mb][nb] = __builtin_amdgcn_mfma_f32_16x16x32_bf16(a[mb], bu[nb], acc[mb][nb], 0, 0, 0);
      }
      // epilogue1: h = tanh(acc + b1)
#pragma unroll
      for (int mb = 0; mb < 4; ++mb)
#pragma unroll
        for (int nb = 0; nb < 4; ++nb) {
          float h0 = tanh_fast(acc[mb][nb][0] + bflo(b1p[mb * 2 + 0]));
          float h1 = tanh_fast(acc[mb][nb][1] + bfhi(b1p[mb * 2 + 0]));
          float h2 = tanh_fast(acc[mb][nb][2] + bflo(b1p[mb * 2 + 1]));
          float h3 = tanh_fast(acc[mb][nb][3] + bfhi(b1p[mb * 2 + 1]));
          u32x2 w; w.x = pk(h0, h1); w.y = pk(h2, h3);
          *(u32x2*)&lds[H_BASE + (nb * 16 + lanel) * HSTR + wv * 64 + mb * 16 + laneq * 4] = w;
        }
      __syncthreads();   // h visible; all GEMM1 u-reads done

      // ---------- GEMM2': D[dcol][row] = W2T(A,global) x h(B,LDS) ----------
      f32x4 acc2[2][4];
#pragma unroll
      for (int mb = 0; mb < 2; ++mb)
#pragma unroll
        for (int nb = 0; nb < 4; ++nb) acc2[mb][nb] = (f32x4){0.f, 0.f, 0.f, 0.f};
#pragma unroll 1
      for (int kk = 0; kk < 16; ++kk) {
        bf16x8 a2[2], bh[4];
#pragma unroll
        for (int mb = 0; mb < 2; ++mb)
          a2[mb] = *(const bf16x8*)(w2base[mb] + kk * 32);
#pragma unroll
        for (int nb = 0; nb < 4; ++nb)
          bh[nb] = *(const bf16x8*)&lds[H_BASE + (nb * 16 + lanel) * HSTR + kk * 32 + laneq * 8];
#pragma unroll
        for (int mb = 0; mb < 2; ++mb)
#pragma unroll
          for (int nb = 0; nb < 4; ++nb)
            acc2[mb][nb] = __builtin_amdgcn_mfma_f32_16x16x32_bf16(a2[mb], bh[nb], acc2[mb][nb], 0, 0, 0);
      }

      // ---------- fused epilogue2 + stage epilogue ----------
      if (s == 1) {
        const float C = DT * 0.2f;
#pragma unroll
        for (int mb = 0; mb < 2; ++mb)
#pragma unroll
          for (int nb = 0; nb < 4; ++nb) {
            int i = nb * 8 + mb * 4, p = nb * 4 + mb * 2;
            float k0 = acc2[mb][nb][0] + bflo(b2p[mb * 2 + 0]);
            float k1 = acc2[mb][nb][1] + bfhi(b2p[mb * 2 + 0]);
            float k2 = acc2[mb][nb][2] + bflo(b2p[mb * 2 + 1]);
            float k3 = acc2[mb][nb][3] + bfhi(b2p[mb * 2 + 1]);
            st[p] = pk(k0, k1); st[p + 1] = pk(k2, k3);
            u32x2 w;
            w.x = pk(yv[i] + C * k0, yv[i + 1] + C * k1);
            w.y = pk(yv[i + 2] + C * k2, yv[i + 3] + C * k3);
            *(u32x2*)&lds[U_BASE + (nb * 16 + lanel) * USTR + wv * 32 + mb * 16 + laneq * 4] = w;
          }
      } else if (s == 2) {
        const float C1 = DT * 0.075f, C2 = DT * 0.225f;
#pragma unroll
        for (int mb = 0; mb < 2; ++mb)
#pragma unroll
          for (int nb = 0; nb < 4; ++nb) {
            int i = nb * 8 + mb * 4, p = nb * 4 + mb * 2;
            float k0 = acc2[mb][nb][0] + bflo(b2p[mb * 2 + 0]);
            float k1 = acc2[mb][nb][1] + bfhi(b2p[mb * 2 + 0]);
            float k2 = acc2[mb][nb][2] + bflo(b2p[mb * 2 + 1]);
            float k3 = acc2[mb][nb][3] + bfhi(b2p[mb * 2 + 1]);
            st[16 + p] = pk(k0, k1); st[16 + p + 1] = pk(k2, k3);
            u32x2 w;
            w.x = pk(yv[i]     + C1 * bflo(st[p])     + C2 * k0,
                     yv[i + 1] + C1 * bfhi(st[p])     + C2 * k1);
            w.y = pk(yv[i + 2] + C1 * bflo(st[p + 1]) + C2 * k2,
                     yv[i + 3] + C1 * bfhi(st[p + 1]) + C2 * k3);
            *(u32x2*)&lds[U_BASE + (nb * 16 + lanel) * USTR + wv * 32 + mb * 16 + laneq * 4] = w;
          }
      } else if (s == 3) {
        const float C1 = DT * (float)(44.0/45.0);
        const float C2 = DT * (float)(-56.0/15.0);
        const float C3 = DT * (float)(32.0/9.0);
#pragma unroll
        for (int mb = 0; mb < 2; ++mb)
#pragma unroll
          for (int nb = 0; nb < 4; ++nb) {
            int i = nb * 8 + mb * 4, p = nb * 4 + mb * 2;
            float k0 = acc2[mb][nb][0] + bflo(b2p[mb * 2 + 0]);
            float k1 = acc2[mb][nb][1] + bfhi(b2p[mb * 2 + 0]);
            float k2 = acc2[mb][nb][2] + bflo(b2p[mb * 2 + 1]);
            float k3 = acc2[mb][nb][3] + bfhi(b2p[mb * 2 + 1]);
            st[32 + p] = pk(k0, k1); st[32 + p + 1] = pk(k2, k3);
            u32x2 w;
            w.x = pk(yv[i]     + C1 * bflo(st[p])     + C2 * bflo(st[16 + p])     + C3 * k0,
                     yv[i + 1] + C1 * bfhi(st[p])     + C2 * bfhi(st[16 + p])     + C3 * k1);
            w.y = pk(yv[i + 2] + C1 * bflo(st[p + 1]) + C2 * bflo(st[16 + p + 1]) + C3 * k2,
                     yv[i + 3] + C1 * bfhi(st[p + 1]) + C2 * bfhi(st[16 + p + 1]) + C3 * k3);
            *(u32x2*)&lds[U_BASE + (nb * 16 + lanel) * USTR + wv * 32 + mb * 16 + laneq * 4] = w;
          }
      } else if (s == 4) {
        // u5; fold k1..k4 into u6-delta and y; k1..k3 die here
        const float C51 = DT * (float)(19372.0/6561.0);
        const float C52 = DT * (float)(-25360.0/2187.0);
        const float C53 = DT * (float)(64448.0/6561.0);
        const float C54 = DT * (float)(-212.0/729.0);
        const float D61 = DT * (float)(9017.0/3168.0  - 35.0/384.0);   // A61-B1
        const float D62 = DT * (float)(-355.0/33.0);                   // A62 (B2=0)
        const float D63 = DT * (float)(46732.0/5247.0 - 500.0/1113.0); // A63-B3
        const float D64 = DT * (float)(49.0/176.0     - 125.0/192.0);  // A64-B4
        const float E1  = DT * (float)(35.0/384.0);
        const float E3  = DT * (float)(500.0/1113.0);
        const float E4  = DT * (float)(125.0/192.0);
#pragma unroll
        for (int mb = 0; mb < 2; ++mb)
#pragma unroll
          for (int nb = 0; nb < 4; ++nb) {
            int i = nb * 8 + mb * 4, p = nb * 4 + mb * 2;
            float k40 = acc2[mb][nb][0] + bflo(b2p[mb * 2 + 0]);
            float k41 = acc2[mb][nb][1] + bfhi(b2p[mb * 2 + 0]);
            float k42 = acc2[mb][nb][2] + bflo(b2p[mb * 2 + 1]);
            float k43 = acc2[mb][nb][3] + bfhi(b2p[mb * 2 + 1]);
            float k10 = bflo(st[p]),      k11 = bfhi(st[p]);
            float k12 = bflo(st[p + 1]),  k13 = bfhi(st[p + 1]);
            float k20 = bflo(st[16 + p]), k21 = bfhi(st[16 + p]);
            float k22 = bflo(st[16 + p + 1]), k23 = bfhi(st[16 + p + 1]);
            float k30 = bflo(st[32 + p]), k31 = bfhi(st[32 + p]);
            float k32 = bflo(st[32 + p + 1]), k33 = bfhi(st[32 + p + 1]);
            u32x2 w;
            w.x = pk(yv[i]     + C51 * k10 + C52 * k20 + C53 * k30 + C54 * k40,
                     yv[i + 1] + C51 * k11 + C52 * k21 + C53 * k31 + C54 * k41);
            w.y = pk(yv[i + 2] + C51 * k12 + C52 * k22 + C53 * k32 + C54 * k42,
                     yv[i + 3] + C51 * k13 + C52 * k23 + C53 * k33 + C54 * k43);
            *(u32x2*)&lds[U_BASE + (nb * 16 + lanel) * USTR + wv * 32 + mb * 16 + laneq * 4] = w;
            st[p]     = pk(D61 * k10 + D62 * k20 + D63 * k30 + D64 * k40,
                           D61 * k11 + D62 * k21 + D63 * k31 + D64 * k41);
            st[p + 1] = pk(D61 * k12 + D62 * k22 + D63 * k32 + D64 * k42,
                           D61 * k13 + D62 * k23 + D63 * k33 + D64 * k43);
            yv[i]     += E1 * k10 + E3 * k30 + E4 * k40;
            yv[i + 1] += E1 * k11 + E3 * k31 + E4 * k41;
            yv[i + 2] += E1 * k12 + E3 * k32 + E4 * k42;
            yv[i + 3] += E1 * k13 + E3 * k33 + E4 * k43;
          }
      } else if (s == 5) {
        const float D65 = DT * (float)(-5103.0/18656.0 + 2187.0/6784.0); // A65-B5
        const float E5  = DT * (float)(-2187.0/6784.0);
#pragma unroll
        for (int mb = 0; mb < 2; ++mb)
#pragma unroll
          for (int nb = 0; nb < 4; ++nb) {
            int i = nb * 8 + mb * 4, p = nb * 4 + mb * 2;
            float k0 = acc2[mb][nb][0] + bflo(b2p[mb * 2 + 0]);
            float k1 = acc2[mb][nb][1] + bfhi(b2p[mb * 2 + 0]);
            float k2 = acc2[mb][nb][2] + bflo(b2p[mb * 2 + 1]);
            float k3 = acc2[mb][nb][3] + bfhi(b2p[mb * 2 + 1]);
            u32x2 w;
            w.x = pk(yv[i]     + bflo(st[p])     + D65 * k0,
                     yv[i + 1] + bfhi(st[p])     + D65 * k1);
            w.y = pk(yv[i + 2] + bflo(st[p + 1]) + D65 * k2,
                     yv[i + 3] + bfhi(st[p + 1]) + D65 * k3);
            *(u32x2*)&lds[U_BASE + (nb * 16 + lanel) * USTR + wv * 32 + mb * 16 + laneq * 4] = w;
            yv[i]     += E5 * k0;
            yv[i + 1] += E5 * k1;
            yv[i + 2] += E5 * k2;
            yv[i + 3] += E5 * k3;
          }
      } else {
        const float E6 = DT * (float)(11.0/84.0);
#pragma unroll
        for (int mb = 0; mb < 2; ++mb)
#pragma unroll
          for (int nb = 0; nb < 4; ++nb) {
            int i = nb * 8 + mb * 4;
            yv[i]     += E6 * (acc2[mb][nb][0] + bflo(b2p[mb * 2 + 0]));
            yv[i + 1] += E6 * (acc2[mb][nb][1] + bfhi(b2p[mb * 2 + 0]));
            yv[i + 2] += E6 * (acc2[mb][nb][2] + bflo(b2p[mb * 2 + 1]));
            yv[i + 3] += E6 * (acc2[mb][nb][3] + bfhi(b2p[mb * 2 + 1]));
            u32x2 w;
            w.x = pk(yv[i], yv[i + 1]); w.y = pk(yv[i + 2], yv[i + 3]);
            *(u32x2*)&lds[U_BASE + (nb * 16 + lanel) * USTR + wv * 32 + mb * 16 + laneq * 4] = w;
          }
      }
      __syncthreads();   // u visible; all GEMM2 h-reads done
    } // stages
  } // steps

  // ---- out[row] = y . Wfc + bfc ----
  {
    float wfcv[8];
#pragma unroll
    for (int mb = 0; mb < 2; ++mb)
#pragma unroll
      for (int r = 0; r < 4; ++r)
        wfcv[mb * 4 + r] = wfc[wv * 32 + mb * 16 + laneq * 4 + r];
    float* redf = (float*)lds;   // safe: last sync drained all U/H readers
    float pr[4];
#pragma unroll
    for (int nb = 0; nb < 4; ++nb) {
      float p = 0.f;
#pragma unroll
      for (int mb = 0; mb < 2; ++mb)
#pragma unroll
        for (int r = 0; r < 4; ++r)
          p += yv[nb * 8 + mb * 4 + r] * wfcv[mb * 4 + r];
      p += __shfl_xor(p, 16);
      p += __shfl_xor(p, 32);
      pr[nb] = p;
    }
    if (laneq == 0) {
#pragma unroll
      for (int nb = 0; nb < 4; ++nb)
        redf[(nb * 16 + lanel) * 8 + wv] = pr[nb];
    }
    __syncthreads();
    if (tid < 64) {
      float s = bfc[0];
#pragma unroll
      for (int w = 0; w < 8; ++w) s += redf[tid * 8 + w];
      out[wg * 64 + tid] = s;
    }
  }
}

extern "C" void kernel_launch(void* const* d_in, const int* in_sizes, int n_in,
                              void* d_out, int out_size, void* d_ws, size_t ws_size,
                              hipStream_t stream) {
  const float* x   = (const float*)d_in[0];
  const float* W1  = (const float*)d_in[1];
  const float* b1  = (const float*)d_in[2];
  const float* W2  = (const float*)d_in[3];
  const float* b2  = (const float*)d_in[4];
  const float* wfc = (const float*)d_in[5];
  const float* bfc = (const float*)d_in[6];
  float* out = (float*)d_out;

  u16* w1t = (u16*)d_ws;                 // [512][256] bf16
  u16* w2t = w1t + DIMH * DIMD;          // [256][512] bf16

  hipLaunchKernelGGL(convert_w, dim3(512), dim3(256), 0, stream, W1, W2, w1t, w2t);
  hipLaunchKernelGGL(ode_fused, dim3(16384 / MTILE), dim3(NTHREADS), 0, stream,
                     x, b1, b2, wfc, bfc, w1t, w2t, out);
}

// Round 6
// 1617.092 us; speedup vs baseline: 1.4515x; 1.1216x over previous
//
#include <hip/hip_runtime.h>

typedef unsigned short u16;
typedef unsigned int   u32;
typedef __bf16 bf16x8 __attribute__((ext_vector_type(8)));
typedef float  f32x4  __attribute__((ext_vector_type(4)));
typedef u32    u32x2  __attribute__((ext_vector_type(2)));

#define DIMD  256
#define DIMH  512
#define MTILE 64
#define NTHREADS 512

// LDS (u16 units). Row strides padded +16B (keeps b128 alignment).
#define USTR 264
#define HSTR 520
#define U_BASE 0
#define H_BASE (MTILE*USTR)             // 16896
#define LDS_U16 (H_BASE + MTILE*HSTR)   // 50176 u16 = 100352 B

#define DT 0.0625f

__device__ __forceinline__ u16 f2bf(float f) {          // RNE fp32->bf16
  u32 u = __float_as_uint(f);
  u += 0x7FFFu + ((u >> 16) & 1u);
  return (u16)(u >> 16);
}
__device__ __forceinline__ u32 pk(float a, float b) {
#if __has_builtin(__builtin_amdgcn_cvt_pk_bf16_f32)
  auto v = __builtin_amdgcn_cvt_pk_bf16_f32(a, b);      // v_cvt_pk_bf16_f32 (RNE)
  u32 r; __builtin_memcpy(&r, &v, 4); return r;
#else
  return (u32)f2bf(a) | ((u32)f2bf(b) << 16);
#endif
}
__device__ __forceinline__ float bflo(u32 p) { return __uint_as_float(p << 16); }
__device__ __forceinline__ float bfhi(u32 p) { return __uint_as_float(p & 0xFFFF0000u); }
__device__ __forceinline__ float tanh_fast(float x) {
  float e = __builtin_amdgcn_exp2f(x * 2.8853900817779268f);  // 2*log2(e)
  return 1.0f - 2.0f * __builtin_amdgcn_rcpf(e + 1.0f);
}

// Barrier that drains ONLY LDS ops (lgkmcnt). __syncthreads() emits
// s_waitcnt vmcnt(0) lgkmcnt(0) which drains our in-flight global weight
// prefetches (the m97-class ~20% stall). Barrier correctness here needs only
// LDS visibility: weights are read-only, global stores happen only at exit.
// 0xC07F = vmcnt(63) expcnt(7) lgkmcnt(0) in gfx9-family encoding.
__device__ __forceinline__ void bar_lds() {
  asm volatile("" ::: "memory");
  __builtin_amdgcn_s_waitcnt(0xC07F);
  __builtin_amdgcn_s_barrier();
  asm volatile("" ::: "memory");
}

// W1[256][512] -> W1T bf16 [hcol=512][k=256]; W2[512][256] -> W2T bf16 [dcol=256][k=512]
__global__ void convert_w(const float* __restrict__ W1, const float* __restrict__ W2,
                          u16* __restrict__ w1t, u16* __restrict__ w2t) {
  int idx = blockIdx.x * 256 + threadIdx.x;
  {
    int n = idx >> 8, k = idx & 255;
    w1t[idx] = f2bf(W1[k * DIMH + n]);
  }
  {
    int n = idx >> 9, k = idx & 511;
    w2t[idx] = f2bf(W2[k * DIMD + n]);
  }
}

__device__ __forceinline__ void mfma_16(f32x4 (&acc)[4][4],
                                        const bf16x8 (&a)[4], const bf16x8 (&b)[4]) {
#pragma unroll
  for (int mb = 0; mb < 4; ++mb)
#pragma unroll
    for (int nb = 0; nb < 4; ++nb)
      acc[mb][nb] = __builtin_amdgcn_mfma_f32_16x16x32_bf16(a[mb], b[nb], acc[mb][nb], 0, 0, 0);
}
__device__ __forceinline__ void mfma_8(f32x4 (&acc)[2][4],
                                       const bf16x8 (&a)[2], const bf16x8 (&b)[4]) {
#pragma unroll
  for (int mb = 0; mb < 2; ++mb)
#pragma unroll
    for (int nb = 0; nb < 4; ++nb)
      acc[mb][nb] = __builtin_amdgcn_mfma_f32_16x16x32_bf16(a[mb], b[nb], acc[mb][nb], 0, 0, 0);
}

// 1 WG/CU (LDS) => 2 waves/SIMD => 256-reg unified budget. kk-loops are
// manually double-buffered by-2 with `unroll 1` outer: bounded in-flight
// fragment regs (no spills) but loads of kk+1 overlap MFMAs of kk.
__global__ __attribute__((amdgpu_flat_work_group_size(NTHREADS, NTHREADS),
                          amdgpu_waves_per_eu(2, 2)))
void ode_fused(
    const float* __restrict__ x,   const float* __restrict__ b1,
    const float* __restrict__ b2,  const float* __restrict__ wfc,
    const float* __restrict__ bfc, const u16* __restrict__ w1t,
    const u16* __restrict__ w2t,   float* __restrict__ out)
{
  __shared__ u16 lds[LDS_U16];
  __shared__ u32 k2f[16 * NTHREADS];     // parked k2 ([j][tid]: conflict-free)

  const int tid   = threadIdx.x;
  const int wg    = blockIdx.x;
  const int wv    = tid >> 6;          // wave 0..7
  const int lane  = tid & 63;
  const int lanel = lane & 15;
  const int laneq = lane >> 4;

  // Per-thread LDS base pointers (all tile accesses become base + imm offset)
  const u16* uRd = &lds[U_BASE + lanel * USTR + laneq * 8];
  const u16* hRd = &lds[H_BASE + lanel * HSTR + laneq * 8];
  u16* uWr = &lds[U_BASE + lanel * USTR + wv * 32 + laneq * 4];
  u16* hWr = &lds[H_BASE + lanel * HSTR + wv * 64 + laneq * 4];

  // Thread's owned positions (= its GEMM2 C/D fragment):
  //   rows:  nb*16 + lanel               (nb 0..3)
  //   dcols: wv*32 + mb*16 + laneq*4 + r (mb 0..1, r 0..3)
  // flat index i = nb*8 + mb*4 + r ; packed pair p = nb*4 + mb*2 + (r>>1)

  u32 b1p[8], b2p[4];
#pragma unroll
  for (int mb = 0; mb < 4; ++mb) {
    int base = wv * 64 + mb * 16 + laneq * 4;
    b1p[mb * 2 + 0] = pk(b1[base + 0], b1[base + 1]);
    b1p[mb * 2 + 1] = pk(b1[base + 2], b1[base + 3]);
  }
#pragma unroll
  for (int mb = 0; mb < 2; ++mb) {
    int base = wv * 32 + mb * 16 + laneq * 4;
    b2p[mb * 2 + 0] = pk(b2[base + 0], b2[base + 1]);
    b2p[mb * 2 + 1] = pk(b2[base + 2], b2[base + 3]);
  }

  // y in fp32 registers (precision anchor)
  float yv[32];
#pragma unroll
  for (int nb = 0; nb < 4; ++nb)
#pragma unroll
    for (int mb = 0; mb < 2; ++mb) {
      const float4 v = *(const float4*)&x[(wg * 64 + nb * 16 + lanel) * DIMD +
                                          wv * 32 + mb * 16 + laneq * 4];
      int i = nb * 8 + mb * 4;
      yv[i + 0] = v.x; yv[i + 1] = v.y; yv[i + 2] = v.z; yv[i + 3] = v.w;
    }

  // write u1 = bf16(y)
#pragma unroll
  for (int nb = 0; nb < 4; ++nb)
#pragma unroll
    for (int mb = 0; mb < 2; ++mb) {
      int i = nb * 8 + mb * 4;
      u32x2 w; w.x = pk(yv[i], yv[i + 1]); w.y = pk(yv[i + 2], yv[i + 3]);
      *(u32x2*)(uWr + nb * 16 * USTR + mb * 16) = w;
    }

  const u16* w1base[4];
#pragma unroll
  for (int mb = 0; mb < 4; ++mb)
    w1base[mb] = w1t + (wv * 64 + mb * 16 + lanel) * DIMD + laneq * 8;
  const u16* w2base[2];
#pragma unroll
  for (int mb = 0; mb < 2; ++mb)
    w2base[mb] = w2t + (wv * 32 + mb * 16 + lanel) * DIMH + laneq * 8;

  auto ldA1 = [&](bf16x8 (&a)[4], int kk) {
#pragma unroll
    for (int mb = 0; mb < 4; ++mb) a[mb] = *(const bf16x8*)(w1base[mb] + kk * 32);
  };
  auto ldB1 = [&](bf16x8 (&b)[4], int kk) {
#pragma unroll
    for (int nb = 0; nb < 4; ++nb) b[nb] = *(const bf16x8*)(uRd + nb * 16 * USTR + kk * 32);
  };
  auto ldA2 = [&](bf16x8 (&a)[2], int kk) {
#pragma unroll
    for (int mb = 0; mb < 2; ++mb) a[mb] = *(const bf16x8*)(w2base[mb] + kk * 32);
  };
  auto ldB2 = [&](bf16x8 (&b)[4], int kk) {
#pragma unroll
    for (int nb = 0; nb < 4; ++nb) b[nb] = *(const bf16x8*)(hRd + nb * 16 * HSTR + kk * 32);
  };

  // Loop-carried k-state (32 u32):
  //   st[0:16)  = k1 packed (s1..s4), then u6d packed (s4..s5)
  //   st[16:32) = k3 packed (s3..s4)
  //   k2 packed lives in k2f (LDS)
  u32 st[32];

  bf16x8 aP1[4];          // GEMM1 kk=0 weight frags, prefetched across barrier
  ldA1(aP1, 0);
  bar_lds();              // u1 visible; weight prefetch stays in flight

#pragma unroll 1
  for (int step = 0; step < 16; ++step) {
#pragma unroll 1
    for (int s = 1; s <= 6; ++s) {
      // ---------- GEMM1': D[hcol][row] = W1T(A,global) x u(B,LDS) ----------
      f32x4 acc[4][4];
#pragma unroll
      for (int mb = 0; mb < 4; ++mb)
#pragma unroll
        for (int nb = 0; nb < 4; ++nb) acc[mb][nb] = (f32x4){0.f, 0.f, 0.f, 0.f};
      bf16x8 aA[4], bA[4], aB[4], bB[4];
#pragma unroll
      for (int mb = 0; mb < 4; ++mb) aA[mb] = aP1[mb];
      ldB1(bA, 0);
#pragma unroll 1
      for (int kk2 = 0; kk2 < 3; ++kk2) {
        ldA1(aB, 2 * kk2 + 1); ldB1(bB, 2 * kk2 + 1);
        mfma_16(acc, aA, bA);
        ldA1(aA, 2 * kk2 + 2); ldB1(bA, 2 * kk2 + 2);
        mfma_16(acc, aB, bB);
      }
      ldA1(aB, 7); ldB1(bB, 7);
      mfma_16(acc, aA, bA);
      bf16x8 aP2[2];
      ldA2(aP2, 0);                   // GEMM2 kk=0 weight prefetch
      mfma_16(acc, aB, bB);

      // epilogue1: h = tanh(acc + b1)
#pragma unroll
      for (int mb = 0; mb < 4; ++mb)
#pragma unroll
        for (int nb = 0; nb < 4; ++nb) {
          float h0 = tanh_fast(acc[mb][nb][0] + bflo(b1p[mb * 2 + 0]));
          float h1 = tanh_fast(acc[mb][nb][1] + bfhi(b1p[mb * 2 + 0]));
          float h2 = tanh_fast(acc[mb][nb][2] + bflo(b1p[mb * 2 + 1]));
          float h3 = tanh_fast(acc[mb][nb][3] + bfhi(b1p[mb * 2 + 1]));
          u32x2 w; w.x = pk(h0, h1); w.y = pk(h2, h3);
          *(u32x2*)(hWr + nb * 16 * HSTR + mb * 16) = w;
        }
      bar_lds();   // h visible; aP2 stays in flight

      // ---------- GEMM2': D[dcol][row] = W2T(A,global) x h(B,LDS) ----------
      f32x4 acc2[2][4];
#pragma unroll
      for (int mb = 0; mb < 2; ++mb)
#pragma unroll
        for (int nb = 0; nb < 4; ++nb) acc2[mb][nb] = (f32x4){0.f, 0.f, 0.f, 0.f};
      bf16x8 cA[2], dA[4], cB[2], dB[4];
#pragma unroll
      for (int mb = 0; mb < 2; ++mb) cA[mb] = aP2[mb];
      ldB2(dA, 0);
#pragma unroll 1
      for (int kk2 = 0; kk2 < 7; ++kk2) {
        ldA2(cB, 2 * kk2 + 1); ldB2(dB, 2 * kk2 + 1);
        mfma_8(acc2, cA, dA);
        ldA2(cA, 2 * kk2 + 2); ldB2(dA, 2 * kk2 + 2);
        mfma_8(acc2, cB, dB);
      }
      ldA2(cB, 15); ldB2(dB, 15);
      mfma_8(acc2, cA, dA);
      ldA1(aP1, 0);                   // next-stage GEMM1 kk=0 weight prefetch
      mfma_8(acc2, cB, dB);

      // ---------- fused epilogue2 + stage epilogue ----------
      if (s == 1) {
        const float C = DT * 0.2f;
#pragma unroll
        for (int mb = 0; mb < 2; ++mb)
#pragma unroll
          for (int nb = 0; nb < 4; ++nb) {
            int i = nb * 8 + mb * 4, p = nb * 4 + mb * 2;
            float k0 = acc2[mb][nb][0] + bflo(b2p[mb * 2 + 0]);
            float k1 = acc2[mb][nb][1] + bfhi(b2p[mb * 2 + 0]);
            float k2 = acc2[mb][nb][2] + bflo(b2p[mb * 2 + 1]);
            float k3 = acc2[mb][nb][3] + bfhi(b2p[mb * 2 + 1]);
            st[p] = pk(k0, k1); st[p + 1] = pk(k2, k3);
            u32x2 w;
            w.x = pk(yv[i] + C * k0, yv[i + 1] + C * k1);
            w.y = pk(yv[i + 2] + C * k2, yv[i + 3] + C * k3);
            *(u32x2*)(uWr + nb * 16 * USTR + mb * 16) = w;
          }
      } else if (s == 2) {
        const float C1 = DT * 0.075f, C2 = DT * 0.225f;
#pragma unroll
        for (int mb = 0; mb < 2; ++mb)
#pragma unroll
          for (int nb = 0; nb < 4; ++nb) {
            int i = nb * 8 + mb * 4, p = nb * 4 + mb * 2;
            float k0 = acc2[mb][nb][0] + bflo(b2p[mb * 2 + 0]);
            float k1 = acc2[mb][nb][1] + bfhi(b2p[mb * 2 + 0]);
            float k2 = acc2[mb][nb][2] + bflo(b2p[mb * 2 + 1]);
            float k3 = acc2[mb][nb][3] + bfhi(b2p[mb * 2 + 1]);
            k2f[p * NTHREADS + tid]       = pk(k0, k1);   // park k2 in LDS
            k2f[(p + 1) * NTHREADS + tid] = pk(k2, k3);
            u32x2 w;
            w.x = pk(yv[i]     + C1 * bflo(st[p])     + C2 * k0,
                     yv[i + 1] + C1 * bfhi(st[p])     + C2 * k1);
            w.y = pk(yv[i + 2] + C1 * bflo(st[p + 1]) + C2 * k2,
                     yv[i + 3] + C1 * bfhi(st[p + 1]) + C2 * k3);
            *(u32x2*)(uWr + nb * 16 * USTR + mb * 16) = w;
          }
      } else if (s == 3) {
        const float C1 = DT * (float)(44.0/45.0);
        const float C2 = DT * (float)(-56.0/15.0);
        const float C3 = DT * (float)(32.0/9.0);
#pragma unroll
        for (int mb = 0; mb < 2; ++mb)
#pragma unroll
          for (int nb = 0; nb < 4; ++nb) {
            int i = nb * 8 + mb * 4, p = nb * 4 + mb * 2;
            float k0 = acc2[mb][nb][0] + bflo(b2p[mb * 2 + 0]);
            float k1 = acc2[mb][nb][1] + bfhi(b2p[mb * 2 + 0]);
            float k2 = acc2[mb][nb][2] + bflo(b2p[mb * 2 + 1]);
            float k3 = acc2[mb][nb][3] + bfhi(b2p[mb * 2 + 1]);
            st[16 + p] = pk(k0, k1); st[16 + p + 1] = pk(k2, k3);
            u32 q0 = k2f[p * NTHREADS + tid], q1 = k2f[(p + 1) * NTHREADS + tid];
            u32x2 w;
            w.x = pk(yv[i]     + C1 * bflo(st[p])     + C2 * bflo(q0) + C3 * k0,
                     yv[i + 1] + C1 * bfhi(st[p])     + C2 * bfhi(q0) + C3 * k1);
            w.y = pk(yv[i + 2] + C1 * bflo(st[p + 1]) + C2 * bflo(q1) + C3 * k2,
                     yv[i + 3] + C1 * bfhi(st[p + 1]) + C2 * bfhi(q1) + C3 * k3);
            *(u32x2*)(uWr + nb * 16 * USTR + mb * 16) = w;
          }
      } else if (s == 4) {
        // u5; fold k1..k4 into u6-delta and y; k1..k3 die here
        const float C51 = DT * (float)(19372.0/6561.0);
        const float C52 = DT * (float)(-25360.0/2187.0);
        const float C53 = DT * (float)(64448.0/6561.0);
        const float C54 = DT * (float)(-212.0/729.0);
        const float D61 = DT * (float)(9017.0/3168.0  - 35.0/384.0);   // A61-B1
        const float D62 = DT * (float)(-355.0/33.0);                   // A62 (B2=0)
        const float D63 = DT * (float)(46732.0/5247.0 - 500.0/1113.0); // A63-B3
        const float D64 = DT * (float)(49.0/176.0     - 125.0/192.0);  // A64-B4
        const float E1  = DT * (float)(35.0/384.0);
        const float E3  = DT * (float)(500.0/1113.0);
        const float E4  = DT * (float)(125.0/192.0);
#pragma unroll
        for (int mb = 0; mb < 2; ++mb)
#pragma unroll
          for (int nb = 0; nb < 4; ++nb) {
            int i = nb * 8 + mb * 4, p = nb * 4 + mb * 2;
            float k40 = acc2[mb][nb][0] + bflo(b2p[mb * 2 + 0]);
            float k41 = acc2[mb][nb][1] + bfhi(b2p[mb * 2 + 0]);
            float k42 = acc2[mb][nb][2] + bflo(b2p[mb * 2 + 1]);
            float k43 = acc2[mb][nb][3] + bfhi(b2p[mb * 2 + 1]);
            float k10 = bflo(st[p]),      k11 = bfhi(st[p]);
            float k12 = bflo(st[p + 1]),  k13 = bfhi(st[p + 1]);
            u32 q0 = k2f[p * NTHREADS + tid], q1 = k2f[(p + 1) * NTHREADS + tid];
            float k20 = bflo(q0), k21 = bfhi(q0);
            float k22 = bflo(q1), k23 = bfhi(q1);
            float k30 = bflo(st[16 + p]),     k31 = bfhi(st[16 + p]);
            float k32 = bflo(st[16 + p + 1]), k33 = bfhi(st[16 + p + 1]);
            u32x2 w;
            w.x = pk(yv[i]     + C51 * k10 + C52 * k20 + C53 * k30 + C54 * k40,
                     yv[i + 1] + C51 * k11 + C52 * k21 + C53 * k31 + C54 * k41);
            w.y = pk(yv[i + 2] + C51 * k12 + C52 * k22 + C53 * k32 + C54 * k42,
                     yv[i + 3] + C51 * k13 + C52 * k23 + C53 * k33 + C54 * k43);
            *(u32x2*)(uWr + nb * 16 * USTR + mb * 16) = w;
            st[p]     = pk(D61 * k10 + D62 * k20 + D63 * k30 + D64 * k40,
                           D61 * k11 + D62 * k21 + D63 * k31 + D64 * k41);
            st[p + 1] = pk(D61 * k12 + D62 * k22 + D63 * k32 + D64 * k42,
                           D61 * k13 + D62 * k23 + D63 * k33 + D64 * k43);
            yv[i]     += E1 * k10 + E3 * k30 + E4 * k40;
            yv[i + 1] += E1 * k11 + E3 * k31 + E4 * k41;
            yv[i + 2] += E1 * k12 + E3 * k32 + E4 * k42;
            yv[i + 3] += E1 * k13 + E3 * k33 + E4 * k43;
          }
      } else if (s == 5) {
        const float D65 = DT * (float)(-5103.0/18656.0 + 2187.0/6784.0); // A65-B5
        const float E5  = DT * (float)(-2187.0/6784.0);
#pragma unroll
        for (int mb = 0; mb < 2; ++mb)
#pragma unroll
          for (int nb = 0; nb < 4; ++nb) {
            int i = nb * 8 + mb * 4, p = nb * 4 + mb * 2;
            float k0 = acc2[mb][nb][0] + bflo(b2p[mb * 2 + 0]);
            float k1 = acc2[mb][nb][1] + bfhi(b2p[mb * 2 + 0]);
            float k2 = acc2[mb][nb][2] + bflo(b2p[mb * 2 + 1]);
            float k3 = acc2[mb][nb][3] + bfhi(b2p[mb * 2 + 1]);
            u32x2 w;
            w.x = pk(yv[i]     + bflo(st[p])     + D65 * k0,
                     yv[i + 1] + bfhi(st[p])     + D65 * k1);
            w.y = pk(yv[i + 2] + bflo(st[p + 1]) + D65 * k2,
                     yv[i + 3] + bfhi(st[p + 1]) + D65 * k3);
            *(u32x2*)(uWr + nb * 16 * USTR + mb * 16) = w;
            yv[i]     += E5 * k0;
            yv[i + 1] += E5 * k1;
            yv[i + 2] += E5 * k2;
            yv[i + 3] += E5 * k3;
          }
      } else {
        const float E6 = DT * (float)(11.0/84.0);
#pragma unroll
        for (int mb = 0; mb < 2; ++mb)
#pragma unroll
          for (int nb = 0; nb < 4; ++nb) {
            int i = nb * 8 + mb * 4;
            yv[i]     += E6 * (acc2[mb][nb][0] + bflo(b2p[mb * 2 + 0]));
            yv[i + 1] += E6 * (acc2[mb][nb][1] + bfhi(b2p[mb * 2 + 0]));
            yv[i + 2] += E6 * (acc2[mb][nb][2] + bflo(b2p[mb * 2 + 1]));
            yv[i + 3] += E6 * (acc2[mb][nb][3] + bfhi(b2p[mb * 2 + 1]));
            u32x2 w;
            w.x = pk(yv[i], yv[i + 1]); w.y = pk(yv[i + 2], yv[i + 3]);
            *(u32x2*)(uWr + nb * 16 * USTR + mb * 16) = w;
          }
      }
      bar_lds();   // u visible; aP1 prefetch stays in flight
    } // stages
  } // steps

  // ---- out[row] = y . Wfc + bfc ----
  {
    float wfcv[8];
#pragma unroll
    for (int mb = 0; mb < 2; ++mb)
#pragma unroll
      for (int r = 0; r < 4; ++r)
        wfcv[mb * 4 + r] = wfc[wv * 32 + mb * 16 + laneq * 4 + r];
    float* redf = (float*)lds;   // safe: last bar_lds drained all U/H readers
    float pr[4];
#pragma unroll
    for (int nb = 0; nb < 4; ++nb) {
      float p = 0.f;
#pragma unroll
      for (int mb = 0; mb < 2; ++mb)
#pragma unroll
        for (int r = 0; r < 4; ++r)
          p += yv[nb * 8 + mb * 4 + r] * wfcv[mb * 4 + r];
      p += __shfl_xor(p, 16);
      p += __shfl_xor(p, 32);
      pr[nb] = p;
    }
    if (laneq == 0) {
#pragma unroll
      for (int nb = 0; nb < 4; ++nb)
        redf[(nb * 16 + lanel) * 8 + wv] = pr[nb];
    }
    __syncthreads();
    if (tid < 64) {
      float s = bfc[0];
#pragma unroll
      for (int w = 0; w < 8; ++w) s += redf[tid * 8 + w];
      out[wg * 64 + tid] = s;
    }
  }
}

extern "C" void kernel_launch(void* const* d_in, const int* in_sizes, int n_in,
                              void* d_out, int out_size, void* d_ws, size_t ws_size,
                              hipStream_t stream) {
  const float* x   = (const float*)d_in[0];
  const float* W1  = (const float*)d_in[1];
  const float* b1  = (const float*)d_in[2];
  const float* W2  = (const float*)d_in[3];
  const float* b2  = (const float*)d_in[4];
  const float* wfc = (const float*)d_in[5];
  const float* bfc = (const float*)d_in[6];
  float* out = (float*)d_out;

  u16* w1t = (u16*)d_ws;                 // [512][256] bf16
  u16* w2t = w1t + DIMH * DIMD;          // [256][512] bf16

  hipLaunchKernelGGL(convert_w, dim3(512), dim3(256), 0, stream, W1, W2, w1t, w2t);
  hipLaunchKernelGGL(ode_fused, dim3(16384 / MTILE), dim3(NTHREADS), 0, stream,
                     x, b1, b2, wfc, bfc, w1t, w2t, out);
}